// Round 8
// baseline (146.920 us; speedup 1.0000x reference)
//
#include <hip/hip_runtime.h>

#define BB 131072
#define DD 512
#define NN 101
#define D4 128                 // float4 per row
#define TOT (BB * D4)          // 16777216 float4 total
#define GBLK 256               // gram blocks (first -> run during ramp)
#define CBLK 2048              // center blocks
#define TOTB (GBLK + CBLK)     // 2304 blocks total
#define STR (CBLK * 256)       // 524288 threads; TOT/STR = 32 iters exactly
#define NPAIR (NN * NN)        // 10201
#define SCALE 1048576.0        // 2^20 fixed-point scale for center accumulator

typedef float f4 __attribute__((ext_vector_type(4)));

// monotone encode/decode: float -> uint preserving order (handles negatives)
__device__ __forceinline__ unsigned int fenc(float f) {
    unsigned int u = __float_as_uint(f);
    return ((int)u < 0) ? ~u : (u | 0x80000000u);
}
__device__ __forceinline__ float fdec(unsigned int k) {
    return ((int)k < 0) ? __uint_as_float(k & 0x7FFFFFFFu) : __uint_as_float(~k);
}

// SINGLE work dispatch (plus a 16B memset). Blocks 0..255: gram pair-dots,
// published via atomicExch (device-coherent). Blocks 256..2303: center MSE
// partial sums, published via ONE deterministic integer atomicAdd per block
// (fixed-point 2^20; integer addition is order-invariant -> bitwise-identical
// result every call). Arrival counter: the 2304th block finalizes inline,
// reading G and acc through device-coherent atomics. One __threadfence per
// block (tid 0), not per thread -- avoids R6's fence storm.
__global__ __launch_bounds__(256, 8) void fused_kernel(
    const f4* __restrict__ emb, const f4* __restrict__ ctr,
    const int* __restrict__ labels,
    unsigned int* __restrict__ counter,      // zeroed each call
    unsigned long long* __restrict__ acc,    // zeroed each call
    float* __restrict__ G,                   // [NPAIR] fully rewritten each call
    float* __restrict__ out)
{
    int lane = threadIdx.x & 63;
    int wid  = threadIdx.x >> 6;

    if (blockIdx.x < GBLK) {
        // ---- gram: one wave per (i,j) pair, grid-stride over 10201 pairs ----
        int w = blockIdx.x * 4 + wid;
        for (int p = w; p < NPAIR; p += GBLK * 4) {
            int i = p / NN;
            int j = p % NN;
            const f4* wi = ctr + i * D4;
            const f4* wj = ctr + j * D4;
            float dot = 0.f;
#pragma unroll
            for (int r = 0; r < 2; r++) {          // D4=128 = 64 lanes x 2
                f4 a = wi[lane + r * 64];
                f4 c = wj[lane + r * 64];
                dot += a.x * c.x + a.y * c.y + a.z * c.z + a.w * c.w;
            }
            for (int off = 32; off > 0; off >>= 1)
                dot += __shfl_down(dot, off);
            if (lane == 0) atomicExch(&G[p], dot); // push to coherent point
        }
    } else {
        // ---- center (MSE) partial sums: contiguous stream, unroll-4 MLP ----
        int b   = blockIdx.x - GBLK;
        int tid = b * 256 + threadIdx.x;
        int d4  = tid & (D4 - 1);          // STR multiple of 128 -> constant
        float local = 0.f;
#pragma unroll 1
        for (int kk = 0; kk < 8; kk++) {   // 32 iters = 8 x unroll-4
            int i0 = tid + (kk * 4 + 0) * STR;
            int i1 = tid + (kk * 4 + 1) * STR;
            int i2 = tid + (kk * 4 + 2) * STR;
            int i3 = tid + (kk * 4 + 3) * STR;
            int l0 = labels[i0 >> 7];      // wave-uniform -> scalar load
            int l1 = labels[i1 >> 7];
            int l2 = labels[i2 >> 7];
            int l3 = labels[i3 >> 7];
            f4 e0 = emb[i0];
            f4 e1 = emb[i1];
            f4 e2 = emb[i2];
            f4 e3 = emb[i3];
            f4 c0 = ctr[l0 * D4 + d4];     // L2-resident (207 KB per XCD)
            f4 c1 = ctr[l1 * D4 + d4];
            f4 c2 = ctr[l2 * D4 + d4];
            f4 c3 = ctr[l3 * D4 + d4];
            f4 t0 = e0 - c0;
            f4 t1 = e1 - c1;
            f4 t2 = e2 - c2;
            f4 t3 = e3 - c3;
            local += t0.x * t0.x + t0.y * t0.y + t0.z * t0.z + t0.w * t0.w;
            local += t1.x * t1.x + t1.y * t1.y + t1.z * t1.z + t1.w * t1.w;
            local += t2.x * t2.x + t2.y * t2.y + t2.z * t2.z + t2.w * t2.w;
            local += t3.x * t3.x + t3.y * t3.y + t3.z * t3.z + t3.w * t3.w;
        }
        for (int off = 32; off > 0; off >>= 1)
            local += __shfl_down(local, off);
        __shared__ float wsum[4];
        if (lane == 0) wsum[wid] = local;
        __syncthreads();
        if (threadIdx.x == 0) {
            float s = wsum[0] + wsum[1] + wsum[2] + wsum[3];
            // deterministic: double holds s*2^20 (~7e10 < 2^53) exactly enough;
            // integer atomic sum is order-invariant.
            atomicAdd(acc, (unsigned long long)(long long)((double)s * SCALE));
        }
    }

    // ---- arrival gate ----
    __syncthreads();                 // all waves' atomics acked (vmcnt drain)
    __shared__ unsigned int gate;
    if (threadIdx.x == 0) {
        __threadfence();             // order this block's atomics before counter
        gate = atomicAdd(counter, 1u);
    }
    __syncthreads();
    if (gate != TOTB - 1) return;    // block-uniform

    // ================= last block: finalize =================
    // dist[i][j] = 1 - G[i][j]/(max(sqrt(G_ii),.1)*max(sqrt(G_jj),.1));
    // diag + |i-j|==1 masked before row-min (masked adds +1e9; unmasked <= 2,
    // so excluding them from the min is exactly equivalent).
    __shared__ float        denom[NN];
    __shared__ unsigned int mbits[NN];
    __shared__ float        dlow[NN];
    __shared__ float        dupp[NN];
    __shared__ float        fsum[4];
    int t = threadIdx.x;

    if (t < NN) mbits[t] = 0xFFFFFFFFu;          // max encoded key
    // diagonal first (coherent atomic reads of G)
    if (t < NN) {
        float g = atomicAdd(&G[t * NN + t], 0.0f);
        denom[t] = fmaxf(sqrtf(g), 0.1f);
    }
    __syncthreads();

    for (int p = t; p < NPAIR; p += 256) {
        int row = p / NN;
        int col = p - row * NN;
        float g = atomicAdd(&G[p], 0.0f);        // coherent read
        float d = 1.0f - g / (denom[row] * denom[col]);
        int diff = row - col;
        if (diff > 1 || diff < -1)
            atomicMin(&mbits[row], fenc(d));     // row-min over unmasked
        else if (diff == 1)  dlow[row] = d;      // dist[row][row-1]
        else if (diff == -1) dupp[row] = d;      // dist[row][row+1]
    }
    __syncthreads();

    float contrib = 0.f;
    if (t >= 1 && t < NN)
        contrib += fmaxf(2.0f * dlow[t] - fdec(mbits[t]), 0.0f);
    if (t < NN - 1)
        contrib += fmaxf(2.0f * dupp[t] - fdec(mbits[t]), 0.0f);
    for (int off = 32; off > 0; off >>= 1)
        contrib += __shfl_down(contrib, off);
    if ((t & 63) == 0) fsum[t >> 6] = contrib;
    __syncthreads();
    if (t == 0) {
        float margin = (fsum[0] + fsum[1] + fsum[2] + fsum[3]) / (float)NN;
        unsigned long long a = atomicAdd(acc, 0ULL);   // coherent read
        double center = (double)a / (SCALE * (double)BB);
        out[0] = margin + (float)center;
    }
}

extern "C" void kernel_launch(void* const* d_in, const int* in_sizes, int n_in,
                              void* d_out, int out_size, void* d_ws, size_t ws_size,
                              hipStream_t stream) {
    const float* emb    = (const float*)d_in[0];
    const float* ctr    = (const float*)d_in[1];
    const int*   labels = (const int*)d_in[2];
    float* out = (float*)d_out;

    unsigned int*       counter = (unsigned int*)d_ws;          // offset 0
    unsigned long long* acc     = (unsigned long long*)((char*)d_ws + 8);
    float*              G       = (float*)((char*)d_ws + 64);   // NPAIR floats

    hipMemsetAsync(d_ws, 0, 16, stream);   // counter + acc (graph-capturable)
    fused_kernel<<<TOTB, 256, 0, stream>>>(
        (const f4*)emb, (const f4*)ctr, labels, counter, acc, G, out);
}

// Round 9
// 76.469 us; speedup vs baseline: 1.9213x; 1.9213x over previous
//
#include <hip/hip_runtime.h>

#define BB 131072
#define DD 512
#define NN 101
#define D4 128                 // float4 per row
#define TOT (BB * D4)          // 16777216 float4 total
#define CBLK 2048              // blocks: exactly 8 per CU, uniform
#define STR (CBLK * 256)       // 524288 threads; TOT/STR = 32 iters exactly
#define NPAIRS 5151            // symmetric pairs i>=j: 101*102/2

typedef float f4 __attribute__((ext_vector_type(4)));

// Two dispatches. Grid = 2048 uniform blocks (8/CU). Each wave first handles
// at most ONE symmetric gram pair (5151 pairs over 8192 waves, ~0.3us uniform
// overhead -- no displaced blocks, no tail extension), then all blocks run the
// center-MSE sweep: contiguous emb stream, unroll-4 MLP, L2-resident ctr gather.
__global__ __launch_bounds__(256, 8) void fused_kernel(
    const f4* __restrict__ emb, const f4* __restrict__ ctr,
    const int* __restrict__ labels,
    float* __restrict__ partial,   // [CBLK]
    float* __restrict__ G)         // [NN*NN]
{
    int lane = threadIdx.x & 63;
    int wid  = threadIdx.x >> 6;

    // ---- gram: one symmetric pair per wave (p < 5151), plain stores ----
    int p = blockIdx.x * 4 + wid;
    if (p < NPAIRS) {
        // decode p -> (i >= j): i = floor((sqrt(8p+1)-1)/2), j = p - i(i+1)/2
        int i = (int)((sqrtf((float)(8 * p + 1)) - 1.0f) * 0.5f);
        while ((i + 1) * (i + 2) / 2 <= p) i++;     // float-rounding fixups
        while (i * (i + 1) / 2 > p) i--;
        int j = p - i * (i + 1) / 2;
        const f4* wi = ctr + i * D4;
        const f4* wj = ctr + j * D4;
        float dot = 0.f;
#pragma unroll
        for (int r = 0; r < 2; r++) {               // D4=128 = 64 lanes x 2
            f4 a = wi[lane + r * 64];
            f4 c = wj[lane + r * 64];
            dot += a.x * c.x + a.y * c.y + a.z * c.z + a.w * c.w;
        }
        for (int off = 32; off > 0; off >>= 1)
            dot += __shfl_down(dot, off);
        if (lane == 0) {
            G[i * NN + j] = dot;
            G[j * NN + i] = dot;                    // symmetric fill
        }
    }

    // ---- center (MSE) partial sums ----
    int b   = blockIdx.x;
    int tid = b * 256 + threadIdx.x;
    int d4  = tid & (D4 - 1);          // STR multiple of 128 -> constant
    float local = 0.f;
#pragma unroll 1
    for (int kk = 0; kk < 8; kk++) {   // 32 iters = 8 x unroll-4
        int i0 = tid + (kk * 4 + 0) * STR;
        int i1 = tid + (kk * 4 + 1) * STR;
        int i2 = tid + (kk * 4 + 2) * STR;
        int i3 = tid + (kk * 4 + 3) * STR;
        int l0 = labels[i0 >> 7];      // wave-uniform -> scalar load
        int l1 = labels[i1 >> 7];
        int l2 = labels[i2 >> 7];
        int l3 = labels[i3 >> 7];
        f4 e0 = emb[i0];
        f4 e1 = emb[i1];
        f4 e2 = emb[i2];
        f4 e3 = emb[i3];
        f4 c0 = ctr[l0 * D4 + d4];     // L2-resident (207 KB per XCD)
        f4 c1 = ctr[l1 * D4 + d4];
        f4 c2 = ctr[l2 * D4 + d4];
        f4 c3 = ctr[l3 * D4 + d4];
        f4 t0 = e0 - c0;
        f4 t1 = e1 - c1;
        f4 t2 = e2 - c2;
        f4 t3 = e3 - c3;
        local += t0.x * t0.x + t0.y * t0.y + t0.z * t0.z + t0.w * t0.w;
        local += t1.x * t1.x + t1.y * t1.y + t1.z * t1.z + t1.w * t1.w;
        local += t2.x * t2.x + t2.y * t2.y + t2.z * t2.z + t2.w * t2.w;
        local += t3.x * t3.x + t3.y * t3.y + t3.z * t3.z + t3.w * t3.w;
    }
    for (int off = 32; off > 0; off >>= 1)
        local += __shfl_down(local, off);
    __shared__ float wsum[4];
    if (lane == 0) wsum[wid] = local;
    __syncthreads();
    if (threadIdx.x == 0)
        partial[b] = wsum[0] + wsum[1] + wsum[2] + wsum[3];
}

// ---------------- finalize: margin from G + center mean from partials ----------
// dist[i][j] = 1 - G[i][j]/(max(sqrt(G_ii),.1)*max(sqrt(G_jj),.1))
// diag + |i-j|==1 are +1e9-masked before the row min; unmasked entries <= 2,
// so skipping j in {t-1,t,t+1} is exactly equivalent.
__global__ __launch_bounds__(256) void finalize_kernel(
    const float* __restrict__ G, const float* __restrict__ partial,
    float* __restrict__ out)
{
    int t = threadIdx.x;

    double dsum = 0.0;
    for (int i = t; i < CBLK; i += 256)
        dsum += (double)partial[i];
    for (int off = 32; off > 0; off >>= 1)
        dsum += __shfl_down(dsum, off);
    __shared__ double dacc[4];
    if ((t & 63) == 0) dacc[t >> 6] = dsum;

    __shared__ float denom[NN];
    __shared__ float mind[NN];
    if (t < NN)
        denom[t] = fmaxf(sqrtf(G[t * NN + t]), 0.1f);
    __syncthreads();
    if (t < NN) {
        float di = denom[t];
        float mn = 1e30f;
        for (int j = 0; j < NN; j++) {
            if (j >= t - 1 && j <= t + 1) continue;
            float d = 1.0f - G[t * NN + j] / (di * denom[j]);
            mn = fminf(mn, d);
        }
        mind[t] = mn;
    }
    __syncthreads();
    float contrib = 0.f;
    if (t >= 1 && t < NN) {        // d_lower[i]=dist[i][i-1] vs min_dist[1:]
        float dl = 1.0f - G[t * NN + (t - 1)] / (denom[t] * denom[t - 1]);
        contrib += fmaxf(2.0f * dl - mind[t], 0.0f);
    }
    if (t < NN - 1) {              // d_upper[i]=dist[i][i+1] vs min_dist[:-1]
        float du = 1.0f - G[t * NN + (t + 1)] / (denom[t] * denom[t + 1]);
        contrib += fmaxf(2.0f * du - mind[t], 0.0f);
    }
    for (int off = 32; off > 0; off >>= 1)
        contrib += __shfl_down(contrib, off);
    __shared__ float wsum2[4];
    if ((t & 63) == 0) wsum2[t >> 6] = contrib;
    __syncthreads();
    if (t == 0) {
        float margin = (wsum2[0] + wsum2[1] + wsum2[2] + wsum2[3]) / (float)NN;
        double center = (dacc[0] + dacc[1] + dacc[2] + dacc[3]) / (double)BB;
        out[0] = margin + (float)center;
    }
}

extern "C" void kernel_launch(void* const* d_in, const int* in_sizes, int n_in,
                              void* d_out, int out_size, void* d_ws, size_t ws_size,
                              hipStream_t stream) {
    const float* emb    = (const float*)d_in[0];
    const float* ctr    = (const float*)d_in[1];
    const int*   labels = (const int*)d_in[2];
    float* out = (float*)d_out;

    float* partial = (float*)d_ws;                          // CBLK floats
    float* G       = (float*)((char*)d_ws + CBLK * 4);      // NN*NN floats
    // Every ws element used is unconditionally rewritten each call -> no memset.

    fused_kernel<<<CBLK, 256, 0, stream>>>(
        (const f4*)emb, (const f4*)ctr, labels, partial, G);
    finalize_kernel<<<1, 256, 0, stream>>>(G, partial, out);
}